// Round 5
// baseline (142.830 us; speedup 1.0000x reference)
//
#include <hip/hip_runtime.h>
#include <math.h>

// Cosine similarity per matching row: out[r] = dot(a[r],b[r]) / (|a[r]||b[r]|),
// D = 256 floats/row, eps-guarded. nrows = 16*4096 = 65536.
//
// Round-5: all reads via __builtin_amdgcn_global_load_lds (async DMA to LDS),
// the one read path measured to exceed the ~3.3 TB/s VGPR-return wall
// (m97: ~13.4 TB/s aggregate). Wave-private double-buffered LDS, NO
// __syncthreads (avoids the compiler's forced vmcnt(0) drain), hand-placed
// s_waitcnt vmcnt(8) so the prefetched 8 KB stays in flight during compute.
//  - 4 rows/wave/iter: 8 DMA calls x 1 KiB (lane i -> ldsbase + 16*i).
//  - compute: 16-lane group per row, 4x ds_read_b128 per operand,
//    4-step butterfly (12 shuffle-adds per 4 rows).
//  - 1024 blocks x 128 thr, 32 KB LDS/block -> 5 blocks/CU, all 1024
//    co-resident, exactly 8 iterations per wave.

#define EPS 1e-12f

typedef float f4 __attribute__((ext_vector_type(4)));

__device__ __forceinline__ void dma16(const f4* g, f4* l) {
    __builtin_amdgcn_global_load_lds(
        (__attribute__((address_space(1))) void*)g,
        (__attribute__((address_space(3))) void*)l,
        16, 0, 0);
}

__global__ __launch_bounds__(128) void cosine_rows_kernel(
    const f4* __restrict__ a4,
    const f4* __restrict__ b4,
    float* __restrict__ out,
    int nrows)
{
    // [wave][buf][a/b][4 rows * 64 f4] = 2*2*2*256 * 16B = 32 KB
    __shared__ f4 lds[2][2][2][256];

    const int w      = threadIdx.x >> 6;
    const int lane   = threadIdx.x & 63;
    const int W      = blockIdx.x * 2 + w;
    const int stride = gridDim.x * 2 * 4;   // rows advanced per iteration

    int base = W * 4;
    if (base < nrows) {
        #pragma unroll
        for (int r = 0; r < 4; ++r)
            dma16(&a4[(base + r) * 64 + lane], &lds[w][0][0][r * 64]);
        #pragma unroll
        for (int r = 0; r < 4; ++r)
            dma16(&b4[(base + r) * 64 + lane], &lds[w][0][1][r * 64]);
    }

    int buf = 0;
    for (; base < nrows; base += stride, buf ^= 1) {
        const int nxt = base + stride;
        if (nxt < nrows) {
            // Prefetch next iteration into the other buffer (8 calls, 8 KB),
            // then wait only for THIS iteration's 8 calls: outstanding after
            // issue = [stage(i):8][store(i-1):<=1][stage(i+1):8]; vmcnt(8)
            // leaves exactly stage(i+1) in flight.
            #pragma unroll
            for (int r = 0; r < 4; ++r)
                dma16(&a4[(nxt + r) * 64 + lane], &lds[w][buf ^ 1][0][r * 64]);
            #pragma unroll
            for (int r = 0; r < 4; ++r)
                dma16(&b4[(nxt + r) * 64 + lane], &lds[w][buf ^ 1][1][r * 64]);
            asm volatile("s_waitcnt vmcnt(8)" ::: "memory");
        } else {
            asm volatile("s_waitcnt vmcnt(0)" ::: "memory");
        }

        // 16-lane group g handles row base+g; lane sl reads f4s sl,sl+16,...
        const int g  = lane >> 4;
        const int sl = lane & 15;
        const f4* __restrict__ ar = &lds[w][buf][0][g * 64];
        const f4* __restrict__ br = &lds[w][buf][1][g * 64];

        float saa = 0.f, sbb = 0.f, sab = 0.f;
        #pragma unroll
        for (int j = 0; j < 4; ++j) {
            const f4 av = ar[sl + 16 * j];
            const f4 bv = br[sl + 16 * j];
            saa = fmaf(av.x, av.x, saa); saa = fmaf(av.y, av.y, saa);
            saa = fmaf(av.z, av.z, saa); saa = fmaf(av.w, av.w, saa);
            sbb = fmaf(bv.x, bv.x, sbb); sbb = fmaf(bv.y, bv.y, sbb);
            sbb = fmaf(bv.z, bv.z, sbb); sbb = fmaf(bv.w, bv.w, sbb);
            sab = fmaf(av.x, bv.x, sab); sab = fmaf(av.y, bv.y, sab);
            sab = fmaf(av.z, bv.z, sab); sab = fmaf(av.w, bv.w, sab);
        }

        // Butterfly within the 16-lane group (xor 1,2,4,8 stays in-group).
        #pragma unroll
        for (int off = 1; off < 16; off <<= 1) {
            saa += __shfl_xor(saa, off, 64);
            sbb += __shfl_xor(sbb, off, 64);
            sab += __shfl_xor(sab, off, 64);
        }

        if (sl == 0) {
            const float denom = sqrtf(fmaxf(saa, EPS)) * sqrtf(fmaxf(sbb, EPS));
            out[base + g] = sab / denom;
        }
    }
}

extern "C" void kernel_launch(void* const* d_in, const int* in_sizes, int n_in,
                              void* d_out, int out_size, void* d_ws, size_t ws_size,
                              hipStream_t stream) {
    const float* a = (const float*)d_in[0];
    const float* b = (const float*)d_in[1];
    float* out = (float*)d_out;

    const int nrows = out_size;   // 65536
    const int blocks = 1024;      // 2048 waves * 4 rows * 8 iters = 65536 rows

    cosine_rows_kernel<<<blocks, 128, 0, stream>>>(
        (const f4*)a, (const f4*)b, out, nrows);
}